// Round 7
// baseline (284.978 us; speedup 1.0000x reference)
//
#include <hip/hip_runtime.h>
#include <stdint.h>
#include <stddef.h>

#define Tq 2048
#define DM 1024

typedef unsigned short u16;
typedef __bf16 bf16x8 __attribute__((ext_vector_type(8)));
typedef float f32x4 __attribute__((ext_vector_type(4)));
typedef unsigned short u16x8 __attribute__((ext_vector_type(8)));
typedef unsigned short u16x4 __attribute__((ext_vector_type(4)));

__device__ __forceinline__ float bf2f(u16 h) {
    union { unsigned int u; float f; } c; c.u = ((unsigned int)h) << 16; return c.f;
}
__device__ __forceinline__ u16 f2bf(float f) {
    union { float f; unsigned int u; } c; c.f = f;
    unsigned int u = c.u;
    return (u16)((u + 0x7fffu + ((u >> 16) & 1u)) >> 16);  // RNE
}

// async global->LDS, 16B per lane; lds base wave-uniform (HW adds lane*16)
#define GLD(gp, lp) __builtin_amdgcn_global_load_lds(                                  \
        (const __attribute__((address_space(1))) void*)(gp),                           \
        (__attribute__((address_space(3))) void*)(lp), 16, 0, 0)

// ---------------------------------------------------------------------------
// Format sniff (round-3 proven).
// ---------------------------------------------------------------------------
__device__ __forceinline__ int sniff_fp32(const u16* xs) {
    const int lane = threadIdx.x & 63;
    const u16 u = xs[lane];
    const int e = (u >> 7) & 0xFF;
    unsigned long long m = __ballot(e >= 160);
    return __popcll(m) >= 4;
}

__device__ __forceinline__ void cvt_body(const void* src, u16* dst, int i0, int fmt) {
    if (fmt) {
        const float* s = (const float*)src;
        float4 a = *(const float4*)(s + i0);
        float4 b = *(const float4*)(s + i0 + 4);
        u16x8 o;
        o[0] = f2bf(a.x); o[1] = f2bf(a.y); o[2] = f2bf(a.z); o[3] = f2bf(a.w);
        o[4] = f2bf(b.x); o[5] = f2bf(b.y); o[6] = f2bf(b.z); o[7] = f2bf(b.w);
        *(u16x8*)(dst + i0) = o;
    } else {
        *(u16x8*)(dst + i0) = *(const u16x8*)((const u16*)src + i0);
    }
}

// ---------------------------------------------------------------------------
// Fused canonicalization: x (blocks 0..4095) + 4 weights/biases (4096..6143).
// ---------------------------------------------------------------------------
__global__ void cvt_all(const void* __restrict__ x,
                        const void* s0, const void* s1, const void* s2, const void* s3,
                        const void* t0, const void* t1, const void* t2, const void* t3,
                        u16* __restrict__ xc, u16* __restrict__ dstW, float* __restrict__ dstB,
                        const u16* __restrict__ xs, int* flag) {
    const int fmt = sniff_fp32(xs);
    int bx = blockIdx.x;
    if (bx < 4096) {
        if (bx == 0 && threadIdx.x == 0) *flag = fmt;
        const int i0 = (bx * 256 + threadIdx.x) * 8;
        cvt_body(x, xc, i0, fmt);
    } else {
        bx -= 4096;
        const int wsel = bx >> 9;          // 0..3
        const int bi   = bx & 511;
        const void* s = (wsel == 0) ? s0 : (wsel == 1) ? s1 : (wsel == 2) ? s2 : s3;
        u16* d = dstW + (size_t)wsel * (DM * DM);
        const int i0 = (bi * 256 + threadIdx.x) * 8;
        cvt_body(s, d, i0, fmt);
        if (bi == 0) {                     // bias piggybacked
            const void* bs = (wsel == 0) ? t0 : (wsel == 1) ? t1 : (wsel == 2) ? t2 : t3;
            float* db = dstB + (size_t)wsel * DM;
            const int j0 = threadIdx.x * 4;
            if (fmt) {
                *(float4*)(db + j0) = *(const float4*)((const float*)bs + j0);
            } else {
                const u16* ss = (const u16*)bs;
                db[j0+0] = bf2f(ss[j0+0]); db[j0+1] = bf2f(ss[j0+1]);
                db[j0+2] = bf2f(ss[j0+2]); db[j0+3] = bf2f(ss[j0+3]);
            }
        }
    }
}

// ---------------------------------------------------------------------------
// GEMM v2 (round 7): BM=128 x BN=256, BK=64, 512 threads (8 waves, 2M x 4N,
// wave tile 64x64). Double-buffered LDS (96 KB), staged 2 K-tiles ahead with
// counted s_waitcnt vmcnt(6) — never drained to 0 in the main loop (T4).
// LDS XOR-swizzle byte^=((row&7)<<4) on BOTH sides (rule #21): pre-swizzled
// global source for the linear global_load_lds dest + swizzled ds_read.
// Verified: involution; fragment reads spread 8 lanes per 16B slot =
// conflict-free. 2 barriers per K-tile but 4x the MFMA of the m97 structure
// between them (8 waves x 32 MFMA). setprio(1) around MFMA clusters (T5).
// Grid: gemm0 (64,12)=768 = 3 exact CU-waves; gemm1 (64,4)=256 = 1 wave.
// mode 0: j>>2 selects Wq/Wk/Wv; Q epilogue folds softmax scale SCQ;
//         V stored transposed (B,H,64,T). mode 1: plain [M,DM] out.
// ---------------------------------------------------------------------------
#define NT 16   // K / 64

__global__ __launch_bounds__(512, 2) void gemm256(
    const u16* __restrict__ A,
    const u16* __restrict__ W0, const u16* __restrict__ W1, const u16* __restrict__ W2,
    const float* __restrict__ b0, const float* __restrict__ b1, const float* __restrict__ b2,
    u16* o0, u16* o1, u16* o2,
    const int* __restrict__ flag, int mode)
{
    __shared__ u16 LB[2][24576];   // per buf: A [0,8192) elems (128x64), B [8192,24576) (256x64)

    const int K = DM;
    const int j = blockIdx.y;
    const int which = (mode == 0) ? (j >> 2) : 0;
    const u16* Wp     = (which == 0) ? W0 : (which == 1) ? W1 : W2;
    const float* bias = (which == 0) ? b0 : (which == 1) ? b1 : b2;
    u16* out          = (which == 0) ? o0 : (which == 1) ? o1 : o2;
    const int jn = (mode == 0) ? (j & 3) : j;
    const int m0 = blockIdx.x * 128, n0 = jn * 256;

    const int tid  = threadIdx.x;
    const int w    = tid >> 6, lane = tid & 63;
    const int wm   = w >> 2, wn = w & 3;
    const int l4   = lane & 15, quad = lane >> 4;
    const int rsub = lane >> 3;                       // 0..7
    const int colE = ((lane & 7) ^ rsub) << 3;        // swizzled source column (elems)

    // stage K-tile kt into buffer bf: 2 A-chunks + 4 B-chunks, 16B/lane each.
    // LDS dest is LINEAR (lane*16 appended by HW); source column pre-swizzled
    // so that the swizzled ds_read below sees A[row][col] (involution).
#define STAGE(kt, bf) do {                                                              \
        const int k0s = (kt) * 64;                                                      \
        _Pragma("unroll")                                                               \
        for (int c = 0; c < 2; ++c) {                                                   \
            const int row = c * 64 + w * 8 + rsub;                                      \
            GLD(A + (size_t)(m0 + row) * K + k0s + colE,                                \
                (char*)&LB[bf][0] + c * 8192 + w * 1024);                               \
        }                                                                               \
        _Pragma("unroll")                                                               \
        for (int c = 0; c < 4; ++c) {                                                   \
            const int row = c * 64 + w * 8 + rsub;                                      \
            GLD(Wp + (size_t)(n0 + row) * K + k0s + colE,                               \
                (char*)&LB[bf][0] + 16384 + c * 8192 + w * 1024);                       \
        }                                                                               \
    } while (0)

    f32x4 acc[4][4] = {};

    STAGE(0, 0);
    STAGE(1, 1);
    asm volatile("s_waitcnt vmcnt(6)" ::: "memory");   // tile 0 landed (tile 1 in flight)
    __syncthreads();

    for (int t = 0; t < NT; ++t) {
        const int cur = t & 1;
        const u16* Ab = &LB[cur][0];
        const u16* Bb = &LB[cur][8192];
        const int swz = (l4 & 7) << 3;

        bf16x8 af[2][4], bf[2][4];
#pragma unroll
        for (int kc = 0; kc < 2; ++kc) {
            const int kq = (kc * 32 + quad * 8);
#pragma unroll
            for (int m = 0; m < 4; ++m)
                af[kc][m] = *(const bf16x8*)&Ab[(wm * 64 + m * 16 + l4) * 64 + (kq ^ swz)];
#pragma unroll
            for (int n = 0; n < 4; ++n)
                bf[kc][n] = *(const bf16x8*)&Bb[(wn * 64 + n * 16 + l4) * 64 + (kq ^ swz)];
        }
        __builtin_amdgcn_s_setprio(1);
#pragma unroll
        for (int kc = 0; kc < 2; ++kc)
#pragma unroll
            for (int m = 0; m < 4; ++m)
#pragma unroll
                for (int n = 0; n < 4; ++n)
                    acc[m][n] = __builtin_amdgcn_mfma_f32_16x16x32_bf16(af[kc][m], bf[kc][n], acc[m][n], 0, 0, 0);
        __builtin_amdgcn_s_setprio(0);

        __syncthreads();                       // all waves done reading buf[cur]
        if (t + 2 < NT) {
            STAGE(t + 2, cur);                 // overwrite the buffer just freed
        }
        if (t + 1 < NT) {
            if (t + 2 < NT) asm volatile("s_waitcnt vmcnt(6)" ::: "memory");
            else            asm volatile("s_waitcnt vmcnt(0)" ::: "memory");
            __syncthreads();                   // every wave's tile-(t+1) loads landed
        }
    }
#undef STAGE

    const int ofmt = (mode == 1) ? *flag : 0;
    const float SCQ = 0.18033688011112042f;    // log2(e)/sqrt(64), folded into Q

#pragma unroll
    for (int n = 0; n < 4; ++n) {
        const int colw = n0 + wn * 64 + n * 16 + l4;
        const float bv = bias[colw];
#pragma unroll
        for (int m = 0; m < 4; ++m) {
            const int mb = m0 + wm * 64 + m * 16 + quad * 4;
            if (mode == 0) {
                const int bb = mb >> 11, t0 = mb & 2047;
                const int h = colw >> 6, d = colw & 63;
                if (which == 2) {
                    // V -> (B,H,64,T) transposed store, 4 consecutive t per 8B
                    u16x4 pk;
#pragma unroll
                    for (int reg = 0; reg < 4; ++reg) pk[reg] = f2bf(acc[m][n][reg] + bv);
                    *(u16x4*)&out[((size_t)(bb * 16 + h) * 64 + d) * 2048 + t0] = pk;
                } else {
                    const float s = (which == 0) ? SCQ : 1.0f;
#pragma unroll
                    for (int reg = 0; reg < 4; ++reg)
                        out[(size_t)((bb * 16 + h) * 2048 + (t0 + reg)) * 64 + d] =
                            f2bf((acc[m][n][reg] + bv) * s);
                }
            } else if (ofmt) {
#pragma unroll
                for (int reg = 0; reg < 4; ++reg)
                    ((float*)out)[(size_t)(mb + reg) * DM + colw] = acc[m][n][reg] + bv;
            } else {
#pragma unroll
                for (int reg = 0; reg < 4; ++reg)
                    out[(size_t)(mb + reg) * DM + colw] = f2bf(acc[m][n][reg] + bv);
            }
        }
    }
}

// ---------------------------------------------------------------------------
// Flash attention v6 (round-6 proven, 88.6 µs) with ONE change: the softmax
// scale is folded into Q by gemm256's epilogue, so p = exp2(sacc) directly.
// Structure: G=4 q-tiles {n,n+8,23-n,31-n}, hoisted kf/vf, Pl[4], diag-only
// masking, K/V double-buffered in LDS (1 staging barrier/kt),
// __launch_bounds__(256,2) for the 256-VGPR budget.
// Round-3/5 lessons: no Pl[2] pipeline (spills), no un-hoisted kf/vf (2x bank
// conflicts), no (256,3)/(256,4) launch bounds (VGPR clamp -> 300MB spill).
// ---------------------------------------------------------------------------
#define LSTR 72

__global__ __launch_bounds__(256, 2) void attn4(
    const u16* __restrict__ Qb, const u16* __restrict__ Kb, const u16* __restrict__ VT,
    const unsigned char* __restrict__ pad,
    u16* __restrict__ Y)
{
    __shared__ u16 Klds[2][64 * LSTR];
    __shared__ u16 Vtl [2][64 * LSTR];
    __shared__ u16 Pl  [4][64 * LSTR];
    __shared__ unsigned char padl[2][64];

    const int nb = blockIdx.y;           // 0..7
    const int bh = blockIdx.x;           // 0..63 -> XCD = bh % 8
    const int b = bh >> 4, h = bh & 15;
    const u16* Qp  = Qb + (size_t)bh * (Tq * 64);
    const u16* Kp  = Kb + (size_t)bh * (Tq * 64);
    const u16* VTp = VT + (size_t)bh * (64 * Tq);

    const int tid = threadIdx.x;
    const int w = tid >> 6, lane = tid & 63;
    const int l4 = lane & 15, quad = lane >> 4;

    const int qt[4] = { nb, nb + 8, 23 - nb, 31 - nb };   // ascending

    bf16x8 qf[4][2];
#pragma unroll
    for (int g = 0; g < 4; ++g) {
        const u16* r = Qp + (size_t)(qt[g] * 64 + w * 16 + l4) * 64 + quad * 8;
        qf[g][0] = *(const bf16x8*)r;
        qf[g][1] = *(const bf16x8*)(r + 32);
    }

    f32x4 o[4][4] = {};
    float l[4][4] = {};

    const int srow = tid >> 2;
    const int sc   = (tid & 3) * 16;

    u16x8 kr0, kr1, vr0, vr1; unsigned char pr = 0;
    {   // tile 0 -> regs
        const u16* kg = Kp + (size_t)srow * 64 + sc;
        kr0 = *(const u16x8*)kg; kr1 = *(const u16x8*)(kg + 8);
        const u16* vg = VTp + (size_t)srow * Tq + sc;
        vr0 = *(const u16x8*)vg; vr1 = *(const u16x8*)(vg + 8);
        if (tid < 64) pr = pad[(size_t)b * Tq + tid];
    }
    // prologue: stage tile 0 into buf 0
    *(u16x8*)&Klds[0][srow * LSTR + sc]     = kr0;
    *(u16x8*)&Klds[0][srow * LSTR + sc + 8] = kr1;
    *(u16x8*)&Vtl [0][srow * LSTR + sc]     = vr0;
    *(u16x8*)&Vtl [0][srow * LSTR + sc + 8] = vr1;
    if (tid < 64) padl[0][tid] = pr;

    const int ktmax = qt[3];

    for (int kt = 0; kt <= ktmax; ++kt) {
        const int cur = kt & 1;
        const int k0 = kt * 64;
        __syncthreads();                       // buf[cur] visible; prev reads done
        if (kt < ktmax) {                      // prefetch next tile into regs
            const u16* kg = Kp + (size_t)(k0 + 64 + srow) * 64 + sc;
            kr0 = *(const u16x8*)kg; kr1 = *(const u16x8*)(kg + 8);
            const u16* vg = VTp + (size_t)srow * Tq + k0 + 64 + sc;
            vr0 = *(const u16x8*)vg; vr1 = *(const u16x8*)(vg + 8);
            if (tid < 64) pr = pad[(size_t)b * Tq + k0 + 64 + tid];
        }

        const bool anypad = __any((int)(padl[cur][lane] != 0));   // wave-uniform

        // ---- QK^T for all active groups; kf shared across groups ----
        bf16x8 kf[2][4];
#pragma unroll
        for (int c = 0; c < 2; ++c)
#pragma unroll
            for (int n = 0; n < 4; ++n)
                kf[c][n] = *(const bf16x8*)&Klds[cur][(n * 16 + l4) * LSTR + c * 32 + quad * 8];

#pragma unroll
        for (int g = 0; g < 4; ++g) {
            if (kt > qt[g]) continue;          // wave-uniform branch
            f32x4 sacc[4] = {};
            __builtin_amdgcn_s_setprio(1);
#pragma unroll
            for (int c = 0; c < 2; ++c)
#pragma unroll
                for (int n = 0; n < 4; ++n)
                    sacc[n] = __builtin_amdgcn_mfma_f32_16x16x32_bf16(qf[g][c], kf[c][n], sacc[n], 0, 0, 0);
            __builtin_amdgcn_s_setprio(0);
            u16* Pg = &Pl[g][0];
            if (kt == qt[g] || anypad) {       // diagonal tile or padding
                bool pm[4];
#pragma unroll
                for (int n = 0; n < 4; ++n) pm[n] = (padl[cur][n * 16 + l4] != 0);
                const int qr = qt[g] * 64 + w * 16 + quad * 4;
#pragma unroll
                for (int r = 0; r < 4; ++r) {
                    float rs = 0.f;
#pragma unroll
                    for (int n = 0; n < 4; ++n) {
                        const int kgi = k0 + n * 16 + l4;
                        const bool msk = (kgi > qr + r) || pm[n];
                        const float p = msk ? 0.0f : exp2f(sacc[n][r]);
                        rs += p;
                        *(__bf16*)&Pg[(w * 16 + quad * 4 + r) * LSTR + n * 16 + l4] = (__bf16)p;
                    }
                    l[g][r] += rs;
                }
            } else {                            // interior, no padding
#pragma unroll
                for (int r = 0; r < 4; ++r) {
                    float rs = 0.f;
#pragma unroll
                    for (int n = 0; n < 4; ++n) {
                        const float p = exp2f(sacc[n][r]);
                        rs += p;
                        *(__bf16*)&Pg[(w * 16 + quad * 4 + r) * LSTR + n * 16 + l4] = (__bf16)p;
                    }
                    l[g][r] += rs;
                }
            }
        }

        // ---- PV for all active groups; vf shared across groups ----
        // No barrier needed: P is wave-private.
        bf16x8 vf[2][4];
#pragma unroll
        for (int c = 0; c < 2; ++c)
#pragma unroll
            for (int t = 0; t < 4; ++t)
                vf[c][t] = *(const bf16x8*)&Vtl[cur][(t * 16 + l4) * LSTR + c * 32 + quad * 8];

#pragma unroll
        for (int g = 0; g < 4; ++g) {
            if (kt > qt[g]) continue;
            __builtin_amdgcn_s_setprio(1);
#pragma unroll
            for (int c = 0; c < 2; ++c) {
                bf16x8 pf = *(const bf16x8*)&Pl[g][(w * 16 + l4) * LSTR + c * 32 + quad * 8];
#pragma unroll
                for (int t = 0; t < 4; ++t)
                    o[g][t] = __builtin_amdgcn_mfma_f32_16x16x32_bf16(pf, vf[c][t], o[g][t], 0, 0, 0);
            }
            __builtin_amdgcn_s_setprio(0);
        }

        if (kt < ktmax) {                      // write-late: stage next tile
            *(u16x8*)&Klds[cur ^ 1][srow * LSTR + sc]     = kr0;
            *(u16x8*)&Klds[cur ^ 1][srow * LSTR + sc + 8] = kr1;
            *(u16x8*)&Vtl [cur ^ 1][srow * LSTR + sc]     = vr0;
            *(u16x8*)&Vtl [cur ^ 1][srow * LSTR + sc + 8] = vr1;
            if (tid < 64) padl[cur ^ 1][tid] = pr;
        }
    }

#pragma unroll
    for (int g = 0; g < 4; ++g)
#pragma unroll
        for (int r = 0; r < 4; ++r)
#pragma unroll
            for (int s = 1; s < 16; s <<= 1)
                l[g][r] += __shfl_xor(l[g][r], s);

#pragma unroll
    for (int g = 0; g < 4; ++g)
#pragma unroll
        for (int r = 0; r < 4; ++r) {
            const float inv = 1.0f / l[g][r];
            u16* y = Y + (size_t)(b * Tq + (qt[g] * 64 + w * 16 + quad * 4 + r)) * DM + h * 64;
#pragma unroll
            for (int t = 0; t < 4; ++t)
                *(__bf16*)&y[t * 16 + l4] = (__bf16)(o[g][t][r] * inv);
        }
}

// ---------------------------------------------------------------------------
extern "C" void kernel_launch(void* const* d_in, const int* in_sizes, int n_in,
                              void* d_out, int out_size, void* d_ws, size_t ws_size,
                              hipStream_t stream) {
    const void* x  = d_in[0];
    const unsigned char* pad = (const unsigned char*)d_in[1];
    const void* Wq = d_in[2];
    const void* bq = d_in[3];
    const void* Wk = d_in[4];
    const void* bk = d_in[5];
    const void* Wv = d_in[6];
    const void* bv = d_in[7];
    const void* Wo = d_in[8];
    const void* bo = d_in[9];
    const u16* xs = (const u16*)x;

    const size_t NEL = (size_t)8192 * 1024;
    const size_t WEL = (size_t)1024 * 1024;

    int* flag   = (int*)d_ws;
    u16* base16 = (u16*)((char*)d_ws + 256);
    u16* xc     = base16;                          // canonical x; reused as Yb
    u16* Wc     = base16 + NEL;                    // Wq,Wk,Wv,Wo
    float* bf_  = (float*)(base16 + NEL + 4*WEL);  // 4 x 1024 fp32 biases
    u16* Qb     = (u16*)(bf_ + 4096);
    u16* Kb     = Qb + NEL;
    u16* VT     = Kb + NEL;                        // (B,H,64,T) — written by gemm0
    u16* Yb     = xc;

    cvt_all<<<dim3(6144), 256, 0, stream>>>(x, Wq, Wk, Wv, Wo, bq, bk, bv, bo,
                                            xc, Wc, bf_, xs, flag);

    gemm256<<<dim3(64, 12), 512, 0, stream>>>(xc, Wc, Wc + WEL, Wc + 2*WEL,
                                              bf_, bf_ + 1024, bf_ + 2048,
                                              Qb, Kb, VT, flag, 0);
    attn4<<<dim3(64, 8), 256, 0, stream>>>(Qb, Kb, VT, pad, Yb);
    gemm256<<<dim3(64, 4), 512, 0, stream>>>(Yb, Wc + 3*WEL, Wc + 3*WEL, Wc + 3*WEL,
                                             bf_ + 3072, bf_ + 3072, bf_ + 3072,
                                             (u16*)d_out, nullptr, nullptr, flag, 1);
}

// Round 8
// 259.632 us; speedup vs baseline: 1.0976x; 1.0976x over previous
//
#include <hip/hip_runtime.h>
#include <stdint.h>
#include <stddef.h>

#define Tq 2048
#define DM 1024

typedef unsigned short u16;
typedef __bf16 bf16x8 __attribute__((ext_vector_type(8)));
typedef float f32x4 __attribute__((ext_vector_type(4)));
typedef unsigned short u16x8 __attribute__((ext_vector_type(8)));
typedef unsigned short u16x4 __attribute__((ext_vector_type(4)));

__device__ __forceinline__ float bf2f(u16 h) {
    union { unsigned int u; float f; } c; c.u = ((unsigned int)h) << 16; return c.f;
}
__device__ __forceinline__ u16 f2bf(float f) {
    union { float f; unsigned int u; } c; c.f = f;
    unsigned int u = c.u;
    return (u16)((u + 0x7fffu + ((u >> 16) & 1u)) >> 16);  // RNE
}

// async global->LDS, 16B per lane; lds base wave-uniform (HW adds lane*16)
#define GLD(gp, lp) __builtin_amdgcn_global_load_lds(                                  \
        (const __attribute__((address_space(1))) void*)(gp),                           \
        (__attribute__((address_space(3))) void*)(lp), 16, 0, 0)

// ---------------------------------------------------------------------------
// Format sniff (round-3 proven).
// ---------------------------------------------------------------------------
__device__ __forceinline__ int sniff_fp32(const u16* xs) {
    const int lane = threadIdx.x & 63;
    const u16 u = xs[lane];
    const int e = (u >> 7) & 0xFF;
    unsigned long long m = __ballot(e >= 160);
    return __popcll(m) >= 4;
}

__device__ __forceinline__ void cvt_body(const void* src, u16* dst, int i0, int fmt) {
    if (fmt) {
        const float* s = (const float*)src;
        float4 a = *(const float4*)(s + i0);
        float4 b = *(const float4*)(s + i0 + 4);
        u16x8 o;
        o[0] = f2bf(a.x); o[1] = f2bf(a.y); o[2] = f2bf(a.z); o[3] = f2bf(a.w);
        o[4] = f2bf(b.x); o[5] = f2bf(b.y); o[6] = f2bf(b.z); o[7] = f2bf(b.w);
        *(u16x8*)(dst + i0) = o;
    } else {
        *(u16x8*)(dst + i0) = *(const u16x8*)((const u16*)src + i0);
    }
}

// ---------------------------------------------------------------------------
// Fused canonicalization: x (blocks 0..4095) + 4 weights/biases (4096..6143).
// ---------------------------------------------------------------------------
__global__ void cvt_all(const void* __restrict__ x,
                        const void* s0, const void* s1, const void* s2, const void* s3,
                        const void* t0, const void* t1, const void* t2, const void* t3,
                        u16* __restrict__ xc, u16* __restrict__ dstW, float* __restrict__ dstB,
                        const u16* __restrict__ xs, int* flag) {
    const int fmt = sniff_fp32(xs);
    int bx = blockIdx.x;
    if (bx < 4096) {
        if (bx == 0 && threadIdx.x == 0) *flag = fmt;
        const int i0 = (bx * 256 + threadIdx.x) * 8;
        cvt_body(x, xc, i0, fmt);
    } else {
        bx -= 4096;
        const int wsel = bx >> 9;          // 0..3
        const int bi   = bx & 511;
        const void* s = (wsel == 0) ? s0 : (wsel == 1) ? s1 : (wsel == 2) ? s2 : s3;
        u16* d = dstW + (size_t)wsel * (DM * DM);
        const int i0 = (bi * 256 + threadIdx.x) * 8;
        cvt_body(s, d, i0, fmt);
        if (bi == 0) {                     // bias piggybacked
            const void* bs = (wsel == 0) ? t0 : (wsel == 1) ? t1 : (wsel == 2) ? t2 : t3;
            float* db = dstB + (size_t)wsel * DM;
            const int j0 = threadIdx.x * 4;
            if (fmt) {
                *(float4*)(db + j0) = *(const float4*)((const float*)bs + j0);
            } else {
                const u16* ss = (const u16*)bs;
                db[j0+0] = bf2f(ss[j0+0]); db[j0+1] = bf2f(ss[j0+1]);
                db[j0+2] = bf2f(ss[j0+2]); db[j0+3] = bf2f(ss[j0+3]);
            }
        }
    }
}

// ---------------------------------------------------------------------------
// GEMM v3 (round 8): same geometry as round 7 (BM=128 x BN=256, BK=64,
// 512 thr / 8 waves 2Mx4N, wave tile 64x64, swizzled LDS — 0 bank conflicts
// measured), but the K-loop is restructured T3-style:
//   * TRIPLE-buffered LDS (3 x 48 KB = 144 KB, 1 block/CU — same as the
//     8-phase template). Tile t+2 is staged into buf[(t+2)%3] DURING the
//     compute phases of tile t — disjoint from buf[t%3] (read) and
//     buf[(t+1)%3] (landing), so no serial stage window exists.
//   * Per K-tile: 2 phases, each {3 GLD issue | 8 ds_read_b128 | setprio(1)
//     16 indep MFMA setprio(0)} — per-phase mix matches m201's template.
//   * ONE barrier per K-tile + per-wave s_waitcnt vmcnt(6) gate (FIFO-oldest:
//     <=6 outstanding => tile t+1's 6 loads, older than t+2's 6, landed).
//     vmcnt(0) only at t=NT-2 (epilogue drain). Wave skew <=1 iter => buf
//     being read is never overwritten (t+3's GLDs issue after next barrier).
// Round-7 lesson kept: swizzle both-sides (involution), epilogues unchanged.
// ---------------------------------------------------------------------------
#define NT 16   // K / 64

__global__ __launch_bounds__(512, 1) void gemm256(
    const u16* __restrict__ A,
    const u16* __restrict__ W0, const u16* __restrict__ W1, const u16* __restrict__ W2,
    const float* __restrict__ b0, const float* __restrict__ b1, const float* __restrict__ b2,
    u16* o0, u16* o1, u16* o2,
    const int* __restrict__ flag, int mode)
{
    __shared__ u16 LB[3][24576];   // per buf: A [0,8192) elems (128x64), B [8192,24576) (256x64)

    const int K = DM;
    const int j = blockIdx.y;
    const int which = (mode == 0) ? (j >> 2) : 0;
    const u16* Wp     = (which == 0) ? W0 : (which == 1) ? W1 : W2;
    const float* bias = (which == 0) ? b0 : (which == 1) ? b1 : b2;
    u16* out          = (which == 0) ? o0 : (which == 1) ? o1 : o2;
    const int jn = (mode == 0) ? (j & 3) : j;
    const int m0 = blockIdx.x * 128, n0 = jn * 256;

    const int tid  = threadIdx.x;
    const int w    = tid >> 6, lane = tid & 63;
    const int wm   = w >> 2, wn = w & 3;
    const int l4   = lane & 15, quad = lane >> 4;
    const int rsub = lane >> 3;                       // 0..7
    const int colE = ((lane & 7) ^ rsub) << 3;        // swizzled source column (elems)

    // STAGE_A: 2 A-chunks + 1st B-chunk (3 GLD). STAGE_B: B-chunks 1..3.
    // LDS dest LINEAR (lane*16 appended by HW); source column pre-swizzled so
    // the swizzled ds_read below recovers A[row][col] (involution).
#define STAGE_A(kt, bf) do {                                                            \
        const int k0s = (kt) * 64;                                                      \
        _Pragma("unroll")                                                               \
        for (int c = 0; c < 2; ++c) {                                                   \
            const int row = c * 64 + w * 8 + rsub;                                      \
            GLD(A + (size_t)(m0 + row) * K + k0s + colE,                                \
                (char*)&LB[bf][0] + c * 8192 + w * 1024);                               \
        }                                                                               \
        {   const int row = w * 8 + rsub;                                               \
            GLD(Wp + (size_t)(n0 + row) * K + k0s + colE,                               \
                (char*)&LB[bf][0] + 16384 + w * 1024); }                                \
    } while (0)
#define STAGE_B(kt, bf) do {                                                            \
        const int k0s = (kt) * 64;                                                      \
        _Pragma("unroll")                                                               \
        for (int c = 1; c < 4; ++c) {                                                   \
            const int row = c * 64 + w * 8 + rsub;                                      \
            GLD(Wp + (size_t)(n0 + row) * K + k0s + colE,                               \
                (char*)&LB[bf][0] + 16384 + c * 8192 + w * 1024);                       \
        }                                                                               \
    } while (0)

    f32x4 acc[4][4] = {};

    STAGE_A(0, 0); STAGE_B(0, 0);
    STAGE_A(1, 1); STAGE_B(1, 1);
    asm volatile("s_waitcnt vmcnt(6)" ::: "memory");   // tile 0 landed (tile 1 in flight)
    __syncthreads();

    for (int t = 0; t < NT; ++t) {
        const int cur = t % 3;
        const int nxt = (t + 2) % 3;
        const u16* Ab = &LB[cur][0];
        const u16* Bb = &LB[cur][8192];
        const int swz = (l4 & 7) << 3;
        const bool pf = (t + 2 < NT);

        // ---- phase A: kc=0, interleaved with first half of t+2 staging ----
        if (pf) STAGE_A(t + 2, nxt);
        {
            bf16x8 af[4], bfr[4];
            const int kq = (quad * 8) ^ swz;
#pragma unroll
            for (int m = 0; m < 4; ++m)
                af[m] = *(const bf16x8*)&Ab[(wm * 64 + m * 16 + l4) * 64 + kq];
#pragma unroll
            for (int n = 0; n < 4; ++n)
                bfr[n] = *(const bf16x8*)&Bb[(wn * 64 + n * 16 + l4) * 64 + kq];
            __builtin_amdgcn_s_setprio(1);
#pragma unroll
            for (int m = 0; m < 4; ++m)
#pragma unroll
                for (int n = 0; n < 4; ++n)
                    acc[m][n] = __builtin_amdgcn_mfma_f32_16x16x32_bf16(af[m], bfr[n], acc[m][n], 0, 0, 0);
            __builtin_amdgcn_s_setprio(0);
        }

        // ---- phase B: kc=1, interleaved with second half of t+2 staging ----
        if (pf) STAGE_B(t + 2, nxt);
        {
            bf16x8 af[4], bfr[4];
            const int kq = (32 + quad * 8) ^ swz;
#pragma unroll
            for (int m = 0; m < 4; ++m)
                af[m] = *(const bf16x8*)&Ab[(wm * 64 + m * 16 + l4) * 64 + kq];
#pragma unroll
            for (int n = 0; n < 4; ++n)
                bfr[n] = *(const bf16x8*)&Bb[(wn * 64 + n * 16 + l4) * 64 + kq];
            __builtin_amdgcn_s_setprio(1);
#pragma unroll
            for (int m = 0; m < 4; ++m)
#pragma unroll
                for (int n = 0; n < 4; ++n)
                    acc[m][n] = __builtin_amdgcn_mfma_f32_16x16x32_bf16(af[m], bfr[n], acc[m][n], 0, 0, 0);
            __builtin_amdgcn_s_setprio(0);
        }

        // ---- gate + barrier (once per K-tile; never drain mid-loop) ----
        if (pf)                asm volatile("s_waitcnt vmcnt(6)" ::: "memory");
        else if (t + 1 < NT)   asm volatile("s_waitcnt vmcnt(0)" ::: "memory");
        if (t + 1 < NT) __syncthreads();
    }
#undef STAGE_A
#undef STAGE_B

    const int ofmt = (mode == 1) ? *flag : 0;
    const float SCQ = 0.18033688011112042f;    // log2(e)/sqrt(64), folded into Q

#pragma unroll
    for (int n = 0; n < 4; ++n) {
        const int colw = n0 + wn * 64 + n * 16 + l4;
        const float bv = bias[colw];
#pragma unroll
        for (int m = 0; m < 4; ++m) {
            const int mb = m0 + wm * 64 + m * 16 + quad * 4;
            if (mode == 0) {
                const int bb = mb >> 11, t0 = mb & 2047;
                const int h = colw >> 6, d = colw & 63;
                if (which == 2) {
                    // V -> (B,H,64,T) transposed store, 4 consecutive t per 8B
                    u16x4 pk;
#pragma unroll
                    for (int reg = 0; reg < 4; ++reg) pk[reg] = f2bf(acc[m][n][reg] + bv);
                    *(u16x4*)&out[((size_t)(bb * 16 + h) * 64 + d) * 2048 + t0] = pk;
                } else {
                    const float s = (which == 0) ? SCQ : 1.0f;
#pragma unroll
                    for (int reg = 0; reg < 4; ++reg)
                        out[(size_t)((bb * 16 + h) * 2048 + (t0 + reg)) * 64 + d] =
                            f2bf((acc[m][n][reg] + bv) * s);
                }
            } else if (ofmt) {
#pragma unroll
                for (int reg = 0; reg < 4; ++reg)
                    ((float*)out)[(size_t)(mb + reg) * DM + colw] = acc[m][n][reg] + bv;
            } else {
#pragma unroll
                for (int reg = 0; reg < 4; ++reg)
                    out[(size_t)(mb + reg) * DM + colw] = f2bf(acc[m][n][reg] + bv);
            }
        }
    }
}

// ---------------------------------------------------------------------------
// Flash attention v6 (round-6/7 proven): softmax scale folded into Q by
// gemm256, G=4 q-tiles {n,n+8,23-n,31-n}, hoisted kf/vf, Pl[4], diag-only
// masking, K/V double-buffered in LDS (1 staging barrier/kt),
// __launch_bounds__(256,2) for the 256-VGPR budget.
// Lessons kept: no Pl[2] pipeline (spills), no un-hoisted kf/vf (2x bank
// conflicts), no (256,3)/(256,4) launch bounds (VGPR clamp -> 300MB spill).
// ---------------------------------------------------------------------------
#define LSTR 72

__global__ __launch_bounds__(256, 2) void attn4(
    const u16* __restrict__ Qb, const u16* __restrict__ Kb, const u16* __restrict__ VT,
    const unsigned char* __restrict__ pad,
    u16* __restrict__ Y)
{
    __shared__ u16 Klds[2][64 * LSTR];
    __shared__ u16 Vtl [2][64 * LSTR];
    __shared__ u16 Pl  [4][64 * LSTR];
    __shared__ unsigned char padl[2][64];

    const int nb = blockIdx.y;           // 0..7
    const int bh = blockIdx.x;           // 0..63 -> XCD = bh % 8
    const int b = bh >> 4, h = bh & 15;
    const u16* Qp  = Qb + (size_t)bh * (Tq * 64);
    const u16* Kp  = Kb + (size_t)bh * (Tq * 64);
    const u16* VTp = VT + (size_t)bh * (64 * Tq);

    const int tid = threadIdx.x;
    const int w = tid >> 6, lane = tid & 63;
    const int l4 = lane & 15, quad = lane >> 4;

    const int qt[4] = { nb, nb + 8, 23 - nb, 31 - nb };   // ascending

    bf16x8 qf[4][2];
#pragma unroll
    for (int g = 0; g < 4; ++g) {
        const u16* r = Qp + (size_t)(qt[g] * 64 + w * 16 + l4) * 64 + quad * 8;
        qf[g][0] = *(const bf16x8*)r;
        qf[g][1] = *(const bf16x8*)(r + 32);
    }

    f32x4 o[4][4] = {};
    float l[4][4] = {};

    const int srow = tid >> 2;
    const int sc   = (tid & 3) * 16;

    u16x8 kr0, kr1, vr0, vr1; unsigned char pr = 0;
    {   // tile 0 -> regs
        const u16* kg = Kp + (size_t)srow * 64 + sc;
        kr0 = *(const u16x8*)kg; kr1 = *(const u16x8*)(kg + 8);
        const u16* vg = VTp + (size_t)srow * Tq + sc;
        vr0 = *(const u16x8*)vg; vr1 = *(const u16x8*)(vg + 8);
        if (tid < 64) pr = pad[(size_t)b * Tq + tid];
    }
    // prologue: stage tile 0 into buf 0
    *(u16x8*)&Klds[0][srow * LSTR + sc]     = kr0;
    *(u16x8*)&Klds[0][srow * LSTR + sc + 8] = kr1;
    *(u16x8*)&Vtl [0][srow * LSTR + sc]     = vr0;
    *(u16x8*)&Vtl [0][srow * LSTR + sc + 8] = vr1;
    if (tid < 64) padl[0][tid] = pr;

    const int ktmax = qt[3];

    for (int kt = 0; kt <= ktmax; ++kt) {
        const int cur = kt & 1;
        const int k0 = kt * 64;
        __syncthreads();                       // buf[cur] visible; prev reads done
        if (kt < ktmax) {                      // prefetch next tile into regs
            const u16* kg = Kp + (size_t)(k0 + 64 + srow) * 64 + sc;
            kr0 = *(const u16x8*)kg; kr1 = *(const u16x8*)(kg + 8);
            const u16* vg = VTp + (size_t)srow * Tq + k0 + 64 + sc;
            vr0 = *(const u16x8*)vg; vr1 = *(const u16x8*)(vg + 8);
            if (tid < 64) pr = pad[(size_t)b * Tq + k0 + 64 + tid];
        }

        const bool anypad = __any((int)(padl[cur][lane] != 0));   // wave-uniform

        // ---- QK^T for all active groups; kf shared across groups ----
        bf16x8 kf[2][4];
#pragma unroll
        for (int c = 0; c < 2; ++c)
#pragma unroll
            for (int n = 0; n < 4; ++n)
                kf[c][n] = *(const bf16x8*)&Klds[cur][(n * 16 + l4) * LSTR + c * 32 + quad * 8];

#pragma unroll
        for (int g = 0; g < 4; ++g) {
            if (kt > qt[g]) continue;          // wave-uniform branch
            f32x4 sacc[4] = {};
            __builtin_amdgcn_s_setprio(1);
#pragma unroll
            for (int c = 0; c < 2; ++c)
#pragma unroll
                for (int n = 0; n < 4; ++n)
                    sacc[n] = __builtin_amdgcn_mfma_f32_16x16x32_bf16(qf[g][c], kf[c][n], sacc[n], 0, 0, 0);
            __builtin_amdgcn_s_setprio(0);
            u16* Pg = &Pl[g][0];
            if (kt == qt[g] || anypad) {       // diagonal tile or padding
                bool pm[4];
#pragma unroll
                for (int n = 0; n < 4; ++n) pm[n] = (padl[cur][n * 16 + l4] != 0);
                const int qr = qt[g] * 64 + w * 16 + quad * 4;
#pragma unroll
                for (int r = 0; r < 4; ++r) {
                    float rs = 0.f;
#pragma unroll
                    for (int n = 0; n < 4; ++n) {
                        const int kgi = k0 + n * 16 + l4;
                        const bool msk = (kgi > qr + r) || pm[n];
                        const float p = msk ? 0.0f : exp2f(sacc[n][r]);
                        rs += p;
                        *(__bf16*)&Pg[(w * 16 + quad * 4 + r) * LSTR + n * 16 + l4] = (__bf16)p;
                    }
                    l[g][r] += rs;
                }
            } else {                            // interior, no padding
#pragma unroll
                for (int r = 0; r < 4; ++r) {
                    float rs = 0.f;
#pragma unroll
                    for (int n = 0; n < 4; ++n) {
                        const float p = exp2f(sacc[n][r]);
                        rs += p;
                        *(__bf16*)&Pg[(w * 16 + quad * 4 + r) * LSTR + n * 16 + l4] = (__bf16)p;
                    }
                    l[g][r] += rs;
                }
            }
        }

        // ---- PV for all active groups; vf shared across groups ----
        // No barrier needed: P is wave-private.
        bf16x8 vf[2][4];
#pragma unroll
        for (int c = 0; c < 2; ++c)
#pragma unroll
            for (int t = 0; t < 4; ++t)
                vf[c][t] = *(const bf16x8*)&Vtl[cur][(t * 16 + l4) * LSTR + c * 32 + quad * 8];

#pragma unroll
        for (int g = 0; g < 4; ++g) {
            if (kt > qt[g]) continue;
            __builtin_amdgcn_s_setprio(1);
#pragma unroll
            for (int c = 0; c < 2; ++c) {
                bf16x8 pf = *(const bf16x8*)&Pl[g][(w * 16 + l4) * LSTR + c * 32 + quad * 8];
#pragma unroll
                for (int t = 0; t < 4; ++t)
                    o[g][t] = __builtin_amdgcn_mfma_f32_16x16x32_bf16(pf, vf[c][t], o[g][t], 0, 0, 0);
            }
            __builtin_amdgcn_s_setprio(0);
        }

        if (kt < ktmax) {                      // write-late: stage next tile
            *(u16x8*)&Klds[cur ^ 1][srow * LSTR + sc]     = kr0;
            *(u16x8*)&Klds[cur ^ 1][srow * LSTR + sc + 8] = kr1;
            *(u16x8*)&Vtl [cur ^ 1][srow * LSTR + sc]     = vr0;
            *(u16x8*)&Vtl [cur ^ 1][srow * LSTR + sc + 8] = vr1;
            if (tid < 64) padl[cur ^ 1][tid] = pr;
        }
    }

#pragma unroll
    for (int g = 0; g < 4; ++g)
#pragma unroll
        for (int r = 0; r < 4; ++r)
#pragma unroll
            for (int s = 1; s < 16; s <<= 1)
                l[g][r] += __shfl_xor(l[g][r], s);

#pragma unroll
    for (int g = 0; g < 4; ++g)
#pragma unroll
        for (int r = 0; r < 4; ++r) {
            const float inv = 1.0f / l[g][r];
            u16* y = Y + (size_t)(b * Tq + (qt[g] * 64 + w * 16 + quad * 4 + r)) * DM + h * 64;
#pragma unroll
            for (int t = 0; t < 4; ++t)
                *(__bf16*)&y[t * 16 + l4] = (__bf16)(o[g][t][r] * inv);
        }
}

// ---------------------------------------------------------------------------
extern "C" void kernel_launch(void* const* d_in, const int* in_sizes, int n_in,
                              void* d_out, int out_size, void* d_ws, size_t ws_size,
                              hipStream_t stream) {
    const void* x  = d_in[0];
    const unsigned char* pad = (const unsigned char*)d_in[1];
    const void* Wq = d_in[2];
    const void* bq = d_in[3];
    const void* Wk = d_in[4];
    const void* bk = d_in[5];
    const void* Wv = d_in[6];
    const void* bv = d_in[7];
    const void* Wo = d_in[8];
    const void* bo = d_in[9];
    const u16* xs = (const u16*)x;

    const size_t NEL = (size_t)8192 * 1024;
    const size_t WEL = (size_t)1024 * 1024;

    int* flag   = (int*)d_ws;
    u16* base16 = (u16*)((char*)d_ws + 256);
    u16* xc     = base16;                          // canonical x; reused as Yb
    u16* Wc     = base16 + NEL;                    // Wq,Wk,Wv,Wo
    float* bf_  = (float*)(base16 + NEL + 4*WEL);  // 4 x 1024 fp32 biases
    u16* Qb     = (u16*)(bf_ + 4096);
    u16* Kb     = Qb + NEL;
    u16* VT     = Kb + NEL;                        // (B,H,64,T) — written by gemm0
    u16* Yb     = xc;

    cvt_all<<<dim3(6144), 256, 0, stream>>>(x, Wq, Wk, Wv, Wo, bq, bk, bv, bo,
                                            xc, Wc, bf_, xs, flag);

    gemm256<<<dim3(64, 12), 512, 0, stream>>>(xc, Wc, Wc + WEL, Wc + 2*WEL,
                                              bf_, bf_ + 1024, bf_ + 2048,
                                              Qb, Kb, VT, flag, 0);
    attn4<<<dim3(64, 8), 256, 0, stream>>>(Qb, Kb, VT, pad, Yb);
    gemm256<<<dim3(64, 4), 512, 0, stream>>>(Yb, Wc + 3*WEL, Wc + 3*WEL, Wc + 3*WEL,
                                             bf_ + 3072, bf_ + 3072, bf_ + 3072,
                                             (u16*)d_out, nullptr, nullptr, flag, 1);
}

// Round 9
// 242.821 us; speedup vs baseline: 1.1736x; 1.0692x over previous
//
#include <hip/hip_runtime.h>
#include <stdint.h>
#include <stddef.h>

#define Tq 2048
#define DM 1024

typedef unsigned short u16;
typedef __bf16 bf16x8 __attribute__((ext_vector_type(8)));
typedef float f32x4 __attribute__((ext_vector_type(4)));
typedef unsigned short u16x8 __attribute__((ext_vector_type(8)));
typedef unsigned short u16x4 __attribute__((ext_vector_type(4)));

__device__ __forceinline__ float bf2f(u16 h) {
    union { unsigned int u; float f; } c; c.u = ((unsigned int)h) << 16; return c.f;
}
__device__ __forceinline__ u16 f2bf(float f) {
    union { float f; unsigned int u; } c; c.f = f;
    unsigned int u = c.u;
    return (u16)((u + 0x7fffu + ((u >> 16) & 1u)) >> 16);  // RNE
}

// bare v_exp_f32 (2^x). exp2f without fast-math expands to the guarded
// __ocml sequence (~5 VALU); softmax inputs are range-safe, so use native.
__device__ __forceinline__ float exp2_native(float x) {
    float r; asm("v_exp_f32 %0, %1" : "=v"(r) : "v"(x)); return r;
}

// async global->LDS, 16B per lane; lds base wave-uniform (HW adds lane*16)
#define GLD(gp, lp) __builtin_amdgcn_global_load_lds(                                  \
        (const __attribute__((address_space(1))) void*)(gp),                           \
        (__attribute__((address_space(3))) void*)(lp), 16, 0, 0)

// ---------------------------------------------------------------------------
// Format sniff (round-3 proven).
// ---------------------------------------------------------------------------
__device__ __forceinline__ int sniff_fp32(const u16* xs) {
    const int lane = threadIdx.x & 63;
    const u16 u = xs[lane];
    const int e = (u >> 7) & 0xFF;
    unsigned long long m = __ballot(e >= 160);
    return __popcll(m) >= 4;
}

__device__ __forceinline__ void cvt_body(const void* src, u16* dst, int i0, int fmt) {
    if (fmt) {
        const float* s = (const float*)src;
        float4 a = *(const float4*)(s + i0);
        float4 b = *(const float4*)(s + i0 + 4);
        u16x8 o;
        o[0] = f2bf(a.x); o[1] = f2bf(a.y); o[2] = f2bf(a.z); o[3] = f2bf(a.w);
        o[4] = f2bf(b.x); o[5] = f2bf(b.y); o[6] = f2bf(b.z); o[7] = f2bf(b.w);
        *(u16x8*)(dst + i0) = o;
    } else {
        *(u16x8*)(dst + i0) = *(const u16x8*)((const u16*)src + i0);
    }
}

// ---------------------------------------------------------------------------
// Fused canonicalization: x (blocks 0..4095) + 4 weights/biases (4096..6143).
// ---------------------------------------------------------------------------
__global__ void cvt_all(const void* __restrict__ x,
                        const void* s0, const void* s1, const void* s2, const void* s3,
                        const void* t0, const void* t1, const void* t2, const void* t3,
                        u16* __restrict__ xc, u16* __restrict__ dstW, float* __restrict__ dstB,
                        const u16* __restrict__ xs, int* flag) {
    const int fmt = sniff_fp32(xs);
    int bx = blockIdx.x;
    if (bx < 4096) {
        if (bx == 0 && threadIdx.x == 0) *flag = fmt;
        const int i0 = (bx * 256 + threadIdx.x) * 8;
        cvt_body(x, xc, i0, fmt);
    } else {
        bx -= 4096;
        const int wsel = bx >> 9;          // 0..3
        const int bi   = bx & 511;
        const void* s = (wsel == 0) ? s0 : (wsel == 1) ? s1 : (wsel == 2) ? s2 : s3;
        u16* d = dstW + (size_t)wsel * (DM * DM);
        const int i0 = (bi * 256 + threadIdx.x) * 8;
        cvt_body(s, d, i0, fmt);
        if (bi == 0) {                     // bias piggybacked
            const void* bs = (wsel == 0) ? t0 : (wsel == 1) ? t1 : (wsel == 2) ? t2 : t3;
            float* db = dstB + (size_t)wsel * DM;
            const int j0 = threadIdx.x * 4;
            if (fmt) {
                *(float4*)(db + j0) = *(const float4*)((const float*)bs + j0);
            } else {
                const u16* ss = (const u16*)bs;
                db[j0+0] = bf2f(ss[j0+0]); db[j0+1] = bf2f(ss[j0+1]);
                db[j0+2] = bf2f(ss[j0+2]); db[j0+3] = bf2f(ss[j0+3]);
            }
        }
    }
}

// ---------------------------------------------------------------------------
// GEMM v3 (round 8, proven): BM=128 x BN=256, BK=64, 512 thr / 8 waves,
// triple-buffered LDS (144 KB), T3 interleave (stage t+2 inside compute
// phases), one barrier per K-tile, counted vmcnt(6), both-sides swizzle
// (0 bank conflicts measured). Do not touch.
// ---------------------------------------------------------------------------
#define NT 16   // K / 64

__global__ __launch_bounds__(512, 1) void gemm256(
    const u16* __restrict__ A,
    const u16* __restrict__ W0, const u16* __restrict__ W1, const u16* __restrict__ W2,
    const float* __restrict__ b0, const float* __restrict__ b1, const float* __restrict__ b2,
    u16* o0, u16* o1, u16* o2,
    const int* __restrict__ flag, int mode)
{
    __shared__ u16 LB[3][24576];   // per buf: A [0,8192) elems (128x64), B [8192,24576) (256x64)

    const int K = DM;
    const int j = blockIdx.y;
    const int which = (mode == 0) ? (j >> 2) : 0;
    const u16* Wp     = (which == 0) ? W0 : (which == 1) ? W1 : W2;
    const float* bias = (which == 0) ? b0 : (which == 1) ? b1 : b2;
    u16* out          = (which == 0) ? o0 : (which == 1) ? o1 : o2;
    const int jn = (mode == 0) ? (j & 3) : j;
    const int m0 = blockIdx.x * 128, n0 = jn * 256;

    const int tid  = threadIdx.x;
    const int w    = tid >> 6, lane = tid & 63;
    const int wm   = w >> 2, wn = w & 3;
    const int l4   = lane & 15, quad = lane >> 4;
    const int rsub = lane >> 3;                       // 0..7
    const int colE = ((lane & 7) ^ rsub) << 3;        // swizzled source column (elems)

#define STAGE_A(kt, bf) do {                                                            \
        const int k0s = (kt) * 64;                                                      \
        _Pragma("unroll")                                                               \
        for (int c = 0; c < 2; ++c) {                                                   \
            const int row = c * 64 + w * 8 + rsub;                                      \
            GLD(A + (size_t)(m0 + row) * K + k0s + colE,                                \
                (char*)&LB[bf][0] + c * 8192 + w * 1024);                               \
        }                                                                               \
        {   const int row = w * 8 + rsub;                                               \
            GLD(Wp + (size_t)(n0 + row) * K + k0s + colE,                               \
                (char*)&LB[bf][0] + 16384 + w * 1024); }                                \
    } while (0)
#define STAGE_B(kt, bf) do {                                                            \
        const int k0s = (kt) * 64;                                                      \
        _Pragma("unroll")                                                               \
        for (int c = 1; c < 4; ++c) {                                                   \
            const int row = c * 64 + w * 8 + rsub;                                      \
            GLD(Wp + (size_t)(n0 + row) * K + k0s + colE,                               \
                (char*)&LB[bf][0] + 16384 + c * 8192 + w * 1024);                       \
        }                                                                               \
    } while (0)

    f32x4 acc[4][4] = {};

    STAGE_A(0, 0); STAGE_B(0, 0);
    STAGE_A(1, 1); STAGE_B(1, 1);
    asm volatile("s_waitcnt vmcnt(6)" ::: "memory");   // tile 0 landed (tile 1 in flight)
    __syncthreads();

    for (int t = 0; t < NT; ++t) {
        const int cur = t % 3;
        const int nxt = (t + 2) % 3;
        const u16* Ab = &LB[cur][0];
        const u16* Bb = &LB[cur][8192];
        const int swz = (l4 & 7) << 3;
        const bool pf = (t + 2 < NT);

        // ---- phase A: kc=0, interleaved with first half of t+2 staging ----
        if (pf) STAGE_A(t + 2, nxt);
        {
            bf16x8 af[4], bfr[4];
            const int kq = (quad * 8) ^ swz;
#pragma unroll
            for (int m = 0; m < 4; ++m)
                af[m] = *(const bf16x8*)&Ab[(wm * 64 + m * 16 + l4) * 64 + kq];
#pragma unroll
            for (int n = 0; n < 4; ++n)
                bfr[n] = *(const bf16x8*)&Bb[(wn * 64 + n * 16 + l4) * 64 + kq];
            __builtin_amdgcn_s_setprio(1);
#pragma unroll
            for (int m = 0; m < 4; ++m)
#pragma unroll
                for (int n = 0; n < 4; ++n)
                    acc[m][n] = __builtin_amdgcn_mfma_f32_16x16x32_bf16(af[m], bfr[n], acc[m][n], 0, 0, 0);
            __builtin_amdgcn_s_setprio(0);
        }

        // ---- phase B: kc=1, interleaved with second half of t+2 staging ----
        if (pf) STAGE_B(t + 2, nxt);
        {
            bf16x8 af[4], bfr[4];
            const int kq = (32 + quad * 8) ^ swz;
#pragma unroll
            for (int m = 0; m < 4; ++m)
                af[m] = *(const bf16x8*)&Ab[(wm * 64 + m * 16 + l4) * 64 + kq];
#pragma unroll
            for (int n = 0; n < 4; ++n)
                bfr[n] = *(const bf16x8*)&Bb[(wn * 64 + n * 16 + l4) * 64 + kq];
            __builtin_amdgcn_s_setprio(1);
#pragma unroll
            for (int m = 0; m < 4; ++m)
#pragma unroll
                for (int n = 0; n < 4; ++n)
                    acc[m][n] = __builtin_amdgcn_mfma_f32_16x16x32_bf16(af[m], bfr[n], acc[m][n], 0, 0, 0);
            __builtin_amdgcn_s_setprio(0);
        }

        // ---- gate + barrier (once per K-tile; never drain mid-loop) ----
        if (pf)                asm volatile("s_waitcnt vmcnt(6)" ::: "memory");
        else if (t + 1 < NT)   asm volatile("s_waitcnt vmcnt(0)" ::: "memory");
        if (t + 1 < NT) __syncthreads();
    }
#undef STAGE_A
#undef STAGE_B

    const int ofmt = (mode == 1) ? *flag : 0;
    const float SCQ = 0.18033688011112042f;    // log2(e)/sqrt(64), folded into Q

#pragma unroll
    for (int n = 0; n < 4; ++n) {
        const int colw = n0 + wn * 64 + n * 16 + l4;
        const float bv = bias[colw];
#pragma unroll
        for (int m = 0; m < 4; ++m) {
            const int mb = m0 + wm * 64 + m * 16 + quad * 4;
            if (mode == 0) {
                const int bb = mb >> 11, t0 = mb & 2047;
                const int h = colw >> 6, d = colw & 63;
                if (which == 2) {
                    // V -> (B,H,64,T) transposed store, 4 consecutive t per 8B
                    u16x4 pk;
#pragma unroll
                    for (int reg = 0; reg < 4; ++reg) pk[reg] = f2bf(acc[m][n][reg] + bv);
                    *(u16x4*)&out[((size_t)(bb * 16 + h) * 64 + d) * 2048 + t0] = pk;
                } else {
                    const float s = (which == 0) ? SCQ : 1.0f;
#pragma unroll
                    for (int reg = 0; reg < 4; ++reg)
                        out[(size_t)((bb * 16 + h) * 2048 + (t0 + reg)) * 64 + d] =
                            f2bf((acc[m][n][reg] + bv) * s);
                }
            } else if (ofmt) {
#pragma unroll
                for (int reg = 0; reg < 4; ++reg)
                    ((float*)out)[(size_t)(mb + reg) * DM + colw] = acc[m][n][reg] + bv;
            } else {
#pragma unroll
                for (int reg = 0; reg < 4; ++reg)
                    out[(size_t)(mb + reg) * DM + colw] = f2bf(acc[m][n][reg] + bv);
            }
        }
    }
}

// ---------------------------------------------------------------------------
// Flash attention v7 — round-8 structure (G=4 q-tiles, hoisted kf/vf, Pl[4],
// diag-only masking, K/V LDS dbuf, SCQ folded into Q, (256,2)) + two VALU
// cuts:
//   1. native v_exp_f32 (exp2_native) instead of exp2f's guarded expansion.
//   2. row-sums via MFMA with a constant all-ones B-fragment:
//      ls[g] = mfma(pf, ones, ls[g]) in the PV c-loop. D[row][col] = rowsum
//      for EVERY col, so each lane holds its rows' sums directly — deletes
//      the 16 adds/group-kt AND the 128-shuffle epilogue reduce. Sum is over
//      bf16-rounded P, consistent with the PV numerator.
// Lessons kept: no Pl[2] pipeline (spills), no un-hoisted kf/vf (2x bank
// conflicts), no (256,3)/(256,4) launch bounds (VGPR clamp -> 300MB spill).
// ---------------------------------------------------------------------------
#define LSTR 72

__global__ __launch_bounds__(256, 2) void attn4(
    const u16* __restrict__ Qb, const u16* __restrict__ Kb, const u16* __restrict__ VT,
    const unsigned char* __restrict__ pad,
    u16* __restrict__ Y)
{
    __shared__ u16 Klds[2][64 * LSTR];
    __shared__ u16 Vtl [2][64 * LSTR];
    __shared__ u16 Pl  [4][64 * LSTR];
    __shared__ unsigned char padl[2][64];

    const int nb = blockIdx.y;           // 0..7
    const int bh = blockIdx.x;           // 0..63 -> XCD = bh % 8
    const int b = bh >> 4, h = bh & 15;
    const u16* Qp  = Qb + (size_t)bh * (Tq * 64);
    const u16* Kp  = Kb + (size_t)bh * (Tq * 64);
    const u16* VTp = VT + (size_t)bh * (64 * Tq);

    const int tid = threadIdx.x;
    const int w = tid >> 6, lane = tid & 63;
    const int l4 = lane & 15, quad = lane >> 4;

    const int qt[4] = { nb, nb + 8, 23 - nb, 31 - nb };   // ascending

    bf16x8 qf[4][2];
#pragma unroll
    for (int g = 0; g < 4; ++g) {
        const u16* r = Qp + (size_t)(qt[g] * 64 + w * 16 + l4) * 64 + quad * 8;
        qf[g][0] = *(const bf16x8*)r;
        qf[g][1] = *(const bf16x8*)(r + 32);
    }

    bf16x8 ones;
#pragma unroll
    for (int e = 0; e < 8; ++e) ones[e] = (__bf16)1.0f;

    f32x4 o[4][4] = {};
    f32x4 ls[4] = {};                    // rowsums via MFMA (all cols equal)

    const int srow = tid >> 2;
    const int sc   = (tid & 3) * 16;

    u16x8 kr0, kr1, vr0, vr1; unsigned char pr = 0;
    {   // tile 0 -> regs
        const u16* kg = Kp + (size_t)srow * 64 + sc;
        kr0 = *(const u16x8*)kg; kr1 = *(const u16x8*)(kg + 8);
        const u16* vg = VTp + (size_t)srow * Tq + sc;
        vr0 = *(const u16x8*)vg; vr1 = *(const u16x8*)(vg + 8);
        if (tid < 64) pr = pad[(size_t)b * Tq + tid];
    }
    // prologue: stage tile 0 into buf 0
    *(u16x8*)&Klds[0][srow * LSTR + sc]     = kr0;
    *(u16x8*)&Klds[0][srow * LSTR + sc + 8] = kr1;
    *(u16x8*)&Vtl [0][srow * LSTR + sc]     = vr0;
    *(u16x8*)&Vtl [0][srow * LSTR + sc + 8] = vr1;
    if (tid < 64) padl[0][tid] = pr;

    const int ktmax = qt[3];

    for (int kt = 0; kt <= ktmax; ++kt) {
        const int cur = kt & 1;
        const int k0 = kt * 64;
        __syncthreads();                       // buf[cur] visible; prev reads done
        if (kt < ktmax) {                      // prefetch next tile into regs
            const u16* kg = Kp + (size_t)(k0 + 64 + srow) * 64 + sc;
            kr0 = *(const u16x8*)kg; kr1 = *(const u16x8*)(kg + 8);
            const u16* vg = VTp + (size_t)srow * Tq + k0 + 64 + sc;
            vr0 = *(const u16x8*)vg; vr1 = *(const u16x8*)(vg + 8);
            if (tid < 64) pr = pad[(size_t)b * Tq + k0 + 64 + tid];
        }

        const bool anypad = __any((int)(padl[cur][lane] != 0));   // wave-uniform

        // ---- QK^T for all active groups; kf shared across groups ----
        bf16x8 kf[2][4];
#pragma unroll
        for (int c = 0; c < 2; ++c)
#pragma unroll
            for (int n = 0; n < 4; ++n)
                kf[c][n] = *(const bf16x8*)&Klds[cur][(n * 16 + l4) * LSTR + c * 32 + quad * 8];

#pragma unroll
        for (int g = 0; g < 4; ++g) {
            if (kt > qt[g]) continue;          // wave-uniform branch
            f32x4 sacc[4] = {};
            __builtin_amdgcn_s_setprio(1);
#pragma unroll
            for (int c = 0; c < 2; ++c)
#pragma unroll
                for (int n = 0; n < 4; ++n)
                    sacc[n] = __builtin_amdgcn_mfma_f32_16x16x32_bf16(qf[g][c], kf[c][n], sacc[n], 0, 0, 0);
            __builtin_amdgcn_s_setprio(0);
            u16* Pg = &Pl[g][0];
            if (kt == qt[g] || anypad) {       // diagonal tile or padding
                bool pm[4];
#pragma unroll
                for (int n = 0; n < 4; ++n) pm[n] = (padl[cur][n * 16 + l4] != 0);
                const int qr = qt[g] * 64 + w * 16 + quad * 4;
#pragma unroll
                for (int r = 0; r < 4; ++r) {
#pragma unroll
                    for (int n = 0; n < 4; ++n) {
                        const int kgi = k0 + n * 16 + l4;
                        const bool msk = (kgi > qr + r) || pm[n];
                        const float p = msk ? 0.0f : exp2_native(sacc[n][r]);
                        *(__bf16*)&Pg[(w * 16 + quad * 4 + r) * LSTR + n * 16 + l4] = (__bf16)p;
                    }
                }
            } else {                            // interior, no padding
#pragma unroll
                for (int r = 0; r < 4; ++r) {
#pragma unroll
                    for (int n = 0; n < 4; ++n) {
                        const float p = exp2_native(sacc[n][r]);
                        *(__bf16*)&Pg[(w * 16 + quad * 4 + r) * LSTR + n * 16 + l4] = (__bf16)p;
                    }
                }
            }
        }

        // ---- PV (+ rowsum MFMA) for all active groups ----
        // No barrier needed: P is wave-private.
        bf16x8 vf[2][4];
#pragma unroll
        for (int c = 0; c < 2; ++c)
#pragma unroll
            for (int t = 0; t < 4; ++t)
                vf[c][t] = *(const bf16x8*)&Vtl[cur][(t * 16 + l4) * LSTR + c * 32 + quad * 8];

#pragma unroll
        for (int g = 0; g < 4; ++g) {
            if (kt > qt[g]) continue;
            __builtin_amdgcn_s_setprio(1);
#pragma unroll
            for (int c = 0; c < 2; ++c) {
                bf16x8 pf = *(const bf16x8*)&Pl[g][(w * 16 + l4) * LSTR + c * 32 + quad * 8];
#pragma unroll
                for (int t = 0; t < 4; ++t)
                    o[g][t] = __builtin_amdgcn_mfma_f32_16x16x32_bf16(pf, vf[c][t], o[g][t], 0, 0, 0);
                ls[g] = __builtin_amdgcn_mfma_f32_16x16x32_bf16(pf, ones, ls[g], 0, 0, 0);
            }
            __builtin_amdgcn_s_setprio(0);
        }

        if (kt < ktmax) {                      // write-late: stage next tile
            *(u16x8*)&Klds[cur ^ 1][srow * LSTR + sc]     = kr0;
            *(u16x8*)&Klds[cur ^ 1][srow * LSTR + sc + 8] = kr1;
            *(u16x8*)&Vtl [cur ^ 1][srow * LSTR + sc]     = vr0;
            *(u16x8*)&Vtl [cur ^ 1][srow * LSTR + sc + 8] = vr1;
            if (tid < 64) padl[cur ^ 1][tid] = pr;
        }
    }

    // ls[g][r] already holds the full rowsum for row (qt[g]*64 + w*16 +
    // quad*4 + r) in every lane (all-ones B => all cols equal): no reduce.
#pragma unroll
    for (int g = 0; g < 4; ++g)
#pragma unroll
        for (int r = 0; r < 4; ++r) {
            const float inv = 1.0f / ls[g][r];
            u16* y = Y + (size_t)(b * Tq + (qt[g] * 64 + w * 16 + quad * 4 + r)) * DM + h * 64;
#pragma unroll
            for (int t = 0; t < 4; ++t)
                *(__bf16*)&y[t * 16 + l4] = (__bf16)(o[g][t][r] * inv);
        }
}

// ---------------------------------------------------------------------------
extern "C" void kernel_launch(void* const* d_in, const int* in_sizes, int n_in,
                              void* d_out, int out_size, void* d_ws, size_t ws_size,
                              hipStream_t stream) {
    const void* x  = d_in[0];
    const unsigned char* pad = (const unsigned char*)d_in[1];
    const void* Wq = d_in[2];
    const void* bq = d_in[3];
    const void* Wk = d_in[4];
    const void* bk = d_in[5];
    const void* Wv = d_in[6];
    const void* bv = d_in[7];
    const void* Wo = d_in[8];
    const void* bo = d_in[9];
    const u16* xs = (const u16*)x;

    const size_t NEL = (size_t)8192 * 1024;
    const size_t WEL = (size_t)1024 * 1024;

    int* flag   = (int*)d_ws;
    u16* base16 = (u16*)((char*)d_ws + 256);
    u16* xc     = base16;                          // canonical x; reused as Yb
    u16* Wc     = base16 + NEL;                    // Wq,Wk,Wv,Wo
    float* bf_  = (float*)(base16 + NEL + 4*WEL);  // 4 x 1024 fp32 biases
    u16* Qb     = (u16*)(bf_ + 4096);
    u16* Kb     = Qb + NEL;
    u16* VT     = Kb + NEL;                        // (B,H,64,T) — written by gemm0
    u16* Yb     = xc;

    cvt_all<<<dim3(6144), 256, 0, stream>>>(x, Wq, Wk, Wv, Wo, bq, bk, bv, bo,
                                            xc, Wc, bf_, xs, flag);

    gemm256<<<dim3(64, 12), 512, 0, stream>>>(xc, Wc, Wc + WEL, Wc + 2*WEL,
                                              bf_, bf_ + 1024, bf_ + 2048,
                                              Qb, Kb, VT, flag, 0);
    attn4<<<dim3(64, 8), 256, 0, stream>>>(Qb, Kb, VT, pad, Yb);
    gemm256<<<dim3(64, 4), 512, 0, stream>>>(Yb, Wc + 3*WEL, Wc + 3*WEL, Wc + 3*WEL,
                                             bf_ + 3072, bf_ + 3072, bf_ + 3072,
                                             (u16*)d_out, nullptr, nullptr, flag, 1);
}